// Round 1
// baseline (28.311 us; speedup 1.0000x reference)
//
#include <hip/hip_runtime.h>

// Problem constants (match reference setup_inputs)
constexpr int B = 8;
constexpr int L = 4096;
constexpr int D = 1024;
constexpr int S = 128;
constexpr int P = L - 64;   // 4032

// One block per (batch, sentence). 256 threads; each thread owns one float4
// column (D/4 = 256). subword2sents is sorted per batch, so the token range
// for sentence s is [lower_bound(s), lower_bound(s+1)).
__global__ __launch_bounds__(256)
void word2sent_pool_kernel(const float* __restrict__ words_emb,
                           const int* __restrict__ bounds,
                           const int* __restrict__ s2s,
                           float* __restrict__ out)
{
    const int blk = blockIdx.x;      // b*S + s
    const int b = blk >> 7;          // / S (S == 128)
    const int s = blk & (S - 1);

    const int* __restrict__ row = s2s + b * P;

    // lower_bound(row, P, s): first idx with row[idx] >= s
    int lo = 0, hi = P;
    while (lo < hi) {
        int m = (lo + hi) >> 1;
        if (row[m] < s) lo = m + 1; else hi = m;
    }
    const int start = lo;

    // lower_bound(row, P, s+1)
    hi = P;
    while (lo < hi) {
        int m = (lo + hi) >> 1;
        if (row[m] < s + 1) lo = m + 1; else hi = m;
    }
    const int cnt = lo - start;

    const int q0 = bounds[b * 2];    // passage start (dynamic slice offset)

    const float4* __restrict__ base = reinterpret_cast<const float4*>(
        words_emb + ((size_t)b * L + (size_t)q0 + (size_t)start) * D);

    const int d4 = threadIdx.x;      // 0..255
    const int rowstride = D / 4;     // 256 float4 per token row

    float4 acc = make_float4(0.f, 0.f, 0.f, 0.f);
    #pragma unroll 4
    for (int t = 0; t < cnt; ++t) {
        float4 v = base[(size_t)t * rowstride + d4];
        acc.x += v.x; acc.y += v.y; acc.z += v.z; acc.w += v.w;
    }

    const float inv = 1.0f / (float)(cnt > 0 ? cnt : 1);
    float4 r = make_float4(acc.x * inv, acc.y * inv, acc.z * inv, acc.w * inv);

    reinterpret_cast<float4*>(out)[(size_t)blk * rowstride + d4] = r;
}

extern "C" void kernel_launch(void* const* d_in, const int* in_sizes, int n_in,
                              void* d_out, int out_size, void* d_ws, size_t ws_size,
                              hipStream_t stream) {
    const float* words_emb = (const float*)d_in[0];   // [B, L, D] f32
    const int* bounds      = (const int*)d_in[1];     // [B, 2] i32
    const int* s2s         = (const int*)d_in[2];     // [B, P] i32 (sorted per row)
    float* out             = (float*)d_out;           // [B, S, D] f32

    dim3 grid(B * S);
    dim3 block(256);
    word2sent_pool_kernel<<<grid, block, 0, stream>>>(words_emb, bounds, s2s, out);
}